// Round 13
// baseline (93.203 us; speedup 1.0000x reference)
//
#include <hip/hip_runtime.h>
#include <hip/hip_fp16.h>
#include <math.h>

typedef unsigned long long u64;

constexpr int B = 512, T = 512, C = 128, L = 64;
constexpr int BLANK = C - 1;      // 127
constexpr float INV_LN2 = 1.44269504088896f;
constexpr float LN2 = 0.69314718055995f;
constexpr int PITCH = 66;         // halves per LDS row in rowstats transpose

// ---------------------------------------------------------------------------
// async global->LDS (Myers staging only)
// ---------------------------------------------------------------------------
typedef const __attribute__((address_space(1))) void* gas_p;
typedef __attribute__((address_space(3))) void* las_p;
__device__ __forceinline__ void gload_lds16(const void* g, void* l) {
  __builtin_amdgcn_global_load_lds((gas_p)g, (las_p)l, 16, 0, 0);
}
#define WAIT_VM0() do { \
  asm volatile("s_waitcnt vmcnt(0)" ::: "memory"); \
  __builtin_amdgcn_sched_barrier(0); } while (0)

// ---------------------------------------------------------------------------
// DPP / lane helpers
// ---------------------------------------------------------------------------
__device__ __forceinline__ float dpp_shr1_f(float x, float old) {
  int r = __builtin_amdgcn_update_dpp(__float_as_int(old), __float_as_int(x),
                                      0x138, 0xf, 0xf, false);  // wave_shr:1
  return __int_as_float(r);
}
__device__ __forceinline__ int dpp_shr1_i(int x, int old) {
  return __builtin_amdgcn_update_dpp(old, x, 0x138, 0xf, 0xf, false);
}
__device__ __forceinline__ float scan_max64(float x) {
  const int NI = (int)0xff800000;  // -inf
  int t;
  t = __builtin_amdgcn_update_dpp(NI, __float_as_int(x), 0x111, 0xf, 0xf, false);
  x = fmaxf(x, __int_as_float(t));
  t = __builtin_amdgcn_update_dpp(NI, __float_as_int(x), 0x112, 0xf, 0xf, false);
  x = fmaxf(x, __int_as_float(t));
  t = __builtin_amdgcn_update_dpp(NI, __float_as_int(x), 0x114, 0xf, 0xf, false);
  x = fmaxf(x, __int_as_float(t));
  t = __builtin_amdgcn_update_dpp(NI, __float_as_int(x), 0x118, 0xf, 0xf, false);
  x = fmaxf(x, __int_as_float(t));
  t = __builtin_amdgcn_update_dpp(NI, __float_as_int(x), 0x142, 0xa, 0xf, false);
  x = fmaxf(x, __int_as_float(t));
  t = __builtin_amdgcn_update_dpp(NI, __float_as_int(x), 0x143, 0xc, 0xf, false);
  x = fmaxf(x, __int_as_float(t));
  return x;  // lane63 = wave max
}
__device__ __forceinline__ float scan_add64(float x) {
  int t;
  t = __builtin_amdgcn_update_dpp(0, __float_as_int(x), 0x111, 0xf, 0xf, false);
  x += __int_as_float(t);
  t = __builtin_amdgcn_update_dpp(0, __float_as_int(x), 0x112, 0xf, 0xf, false);
  x += __int_as_float(t);
  t = __builtin_amdgcn_update_dpp(0, __float_as_int(x), 0x114, 0xf, 0xf, false);
  x += __int_as_float(t);
  t = __builtin_amdgcn_update_dpp(0, __float_as_int(x), 0x118, 0xf, 0xf, false);
  x += __int_as_float(t);
  t = __builtin_amdgcn_update_dpp(0, __float_as_int(x), 0x142, 0xa, 0xf, false);
  x += __int_as_float(t);
  t = __builtin_amdgcn_update_dpp(0, __float_as_int(x), 0x143, 0xc, 0xf, false);
  x += __int_as_float(t);
  return x;  // lane63 = wave sum
}
__device__ __forceinline__ float readlane63(float x) {
  return __int_as_float(__builtin_amdgcn_readlane(__float_as_int(x), 63));
}
__device__ __forceinline__ float readlane_f(float v, int k) {
  return __int_as_float(__builtin_amdgcn_readlane(__float_as_int(v), k));
}

// ---------------------------------------------------------------------------
// K1: per-(b,t) row stats. Writes PROBABILITIES:
//   p_lab[b][j][t] f16 TRANSPOSED (lane-j t-contiguous; via LDS transpose)
//   p_bl[b][t] f32 (blank prob), predc[b][t] u8 argmax,
//   eqm[b][t] u64 = ballot(labels[b][j]==pred) (Myers Peq row, free).
// Grid: blockIdx = chunk*512 + b  (all chunks of sample b on XCD b%8).
// ---------------------------------------------------------------------------
__global__ __launch_bounds__(256) void rowstats_kernel(
    const float* __restrict__ logits, const int* __restrict__ labels,
    __half* __restrict__ p_lab, float* __restrict__ p_bl,
    unsigned char* __restrict__ predc, u64* __restrict__ eqm) {
  __shared__ __half slp[64 * PITCH];
  int b = blockIdx.x & 511;
  int t0 = (blockIdx.x >> 9) << 6;
  int w = threadIdx.x >> 6;
  int lane = threadIdx.x & 63;
  int lab = labels[((size_t)b << 6) + lane];
  for (int i = 0; i < 16; ++i) {
    int t = t0 + w * 16 + i;
    const float* rp = logits + (size_t)(b * T + t) * C;
    float v1 = rp[lane];
    float v2 = rp[lane + 64];
    float m = readlane63(scan_max64(fmaxf(v1, v2)));
    unsigned long long b1 = __ballot(v1 == m);
    unsigned long long b2 = __ballot(v2 == m);
    int idx = b1 ? (__ffsll(b1) - 1) : (64 + __ffsll(b2) - 1);
    u64 eqmask = __ballot(lab == idx);
    float e1 = __builtin_amdgcn_exp2f((v1 - m) * INV_LN2);
    float e2 = __builtin_amdgcn_exp2f((v2 - m) * INV_LN2);
    float rs = __builtin_amdgcn_rcpf(readlane63(scan_add64(e1 + e2)));
    float p1 = e1 * rs;   // prob of class `lane`
    float p2 = e2 * rs;   // prob of class `lane+64`
    float g1 = __shfl(p1, lab & 63);
    float g2 = __shfl(p2, lab & 63);
    float gp = (lab < 64) ? g1 : g2;
    slp[lane * PITCH + (t - t0)] = __float2half(gp);
    if (lane == 63) p_bl[b * T + t] = p2;   // class 127 = blank (f32)
    if (lane == 0) { predc[b * T + t] = (unsigned char)idx; eqm[b * T + t] = eqmask; }
  }
  __syncthreads();
  // writeout: thread k -> (j = k/4, quarter q = k%4): 32B of row j
  int j = threadIdx.x >> 2, q = threadIdx.x & 3;
  unsigned wbuf[8];
#pragma unroll
  for (int wd = 0; wd < 8; ++wd)
    wbuf[wd] = ((const unsigned*)slp)[j * (PITCH / 2) + q * 8 + wd];
  uint4 o0 = make_uint4(wbuf[0], wbuf[1], wbuf[2], wbuf[3]);
  uint4 o1 = make_uint4(wbuf[4], wbuf[5], wbuf[6], wbuf[7]);
  uint4* dst = (uint4*)(p_lab + ((size_t)((b << 6) + j)) * T + t0 + q * 16);
  dst[0] = o0;
  dst[1] = o1;
}

// ---------------------------------------------------------------------------
// CTC alpha step, probability domain with PER-LANE block-floating-point
// (R12-proven numerics). Lane j holds {state 2j+1 = qO, state 2j+2 = qE}
// scaled by 2^m. State 0 = scalar chain (q0, m0).
// ---------------------------------------------------------------------------
__device__ __forceinline__ void ctc_step_p(float pl, float pb, bool skip_ok,
                                           float& qE, float& qO, int& m,
                                           float& q0, int& m0) {
  float pE = dpp_shr1_f(qE, q0);     // neighbor qE (lane0 <- q0)
  float pO = dpp_shr1_f(qO, 0.0f);   // neighbor qO (lane0 <- none)
  int mN = dpp_shr1_i(m, m0);        // neighbor scale (lane0 <- m0)
  int dm = mN - m;                   // constant within a renorm group
  float pEs = ldexpf(pE, dm);
  float pOs = ldexpf(pO, dm);
  float a3 = skip_ok ? pOs : 0.0f;
  float nO = (qO + pEs + a3) * pl;   // odd state 2j+1
  float nE = (qE + qO) * pb;         // even state 2j+2 (in-lane only)
  q0 *= pb;
  qE = nE; qO = nO;
}

// per-lane renorm (every 4 steps): exact power-of-2; dead lanes adopt the
// left neighbor's scale so frontier arrivals never flush.
__device__ __forceinline__ void renorm_q(float& qE, float& qO, int& m,
                                         float& q0, int& m0) {
  float mx = fmaxf(qE, qO);
  int mprev = dpp_shr1_i(m, m0);
  int e = (__float_as_int(mx) >> 23) & 0xff;
  bool dead = (mx == 0.0f);
  int sh = e - 127;
  qE = ldexpf(qE, -sh);
  qO = ldexpf(qO, -sh);
  m = dead ? mprev : (m + sh);
  int e0 = ((__float_as_int(q0) >> 23) & 0xff) - 127;
  q0 = ldexpf(q0, -e0);
  m0 += e0;
}

// extract half #k (0..63) from an 8x uint4 register buffer (k const)
__device__ __forceinline__ float geth64(const uint4 (&buf)[8], int k) {
  const uint4& v = buf[k >> 3];
  int c2 = (k >> 1) & 3;
  unsigned comp = (c2 == 0) ? v.x : (c2 == 1) ? v.y : (c2 == 2) ? v.z : v.w;
  unsigned hs = (k & 1) ? (comp >> 16) : (comp & 0xffffu);
  unsigned short us = (unsigned short)hs;
  __half h;
  __builtin_memcpy(&h, &us, 2);
  return __half2float(h);
}

// Myers/Hyyrö bit-parallel Levenshtein step (lane = one sample; select-only).
__device__ __forceinline__ void ed_step(u64 eq, int cc, int shift, bool tok,
                                        u64& Pv, u64& Mv, int& score, int& prevc) {
  bool keep = (cc != BLANK) && (cc != prevc) && tok;
  u64 Xv = eq | Mv;
  u64 Xh = (((eq & Pv) + Pv) ^ Pv) | eq;
  u64 Ph = Mv | ~(Xh | Pv);
  u64 Mh = Pv & Xh;
  int d = (int)((Ph >> shift) & 1ULL) - (int)((Mh >> shift) & 1ULL);
  score += keep ? d : 0;
  Ph = (Ph << 1) | 1ULL;
  Mh <<= 1;
  u64 nPv = Mh | ~(Xv | Ph);
  u64 nMv = Ph & Xv;
  Pv = keep ? nPv : Pv;
  Mv = keep ? nMv : Mv;
  prevc = cc;
}

// ---------------------------------------------------------------------------
// K2 fused. Blocks [0,8): Myers edit distance (lane = sample, LDS-staged,
// R12-proven). Blocks [8,8+B): CTC — NO LDS: lane j's 64-step operand chunk
// is 128B contiguous (transposed p_lab) -> 8 dwordx4 to VGPRs, double-
// buffered; p_bl via one dword/lane + per-step v_readlane broadcast.
// ---------------------------------------------------------------------------
__global__ __launch_bounds__(64, 1) void dp_kernel(
    const __half* __restrict__ p_lab, const float* __restrict__ p_bl,
    const unsigned char* __restrict__ predc, const u64* __restrict__ eqm,
    const int* __restrict__ labels, const int* __restrict__ label_len,
    const int* __restrict__ logit_len,
    float* __restrict__ loss_b, float* __restrict__ ler_b) {
  __shared__ char smem[36864];   // used by Myers blocks only
  int lane = threadIdx.x;

  if (blockIdx.x >= 8) {
    // ---------------- CTC path (XCD b%8 matches rowstats writer) ----------
    int b = blockIdx.x - 8;
    int tl = logit_len[b];
    int ll = label_len[b];
    int lab = labels[((size_t)b << 6) + lane];
    int labp = __shfl_up(lab, 1);
    bool skip_ok = (lane > 0) && (lab != labp);
    const uint4* pl4 = (const uint4*)(p_lab + ((size_t)((b << 6) + lane)) * T);
    const float* pbb = p_bl + (size_t)b * T;
    float qE = 0.0f, qO, q0;
    int m = 0, m0 = 0;

#define CONSUME(BUF, SBUF) \
    _Pragma("unroll") \
    for (int g = 0; g < 16; ++g) { \
      _Pragma("unroll") \
      for (int kk = 0; kk < 4; ++kk) { \
        int k = g * 4 + kk; \
        ctc_step_p(geth64(BUF, k), readlane_f(SBUF, k), skip_ok, \
                   qE, qO, m, q0, m0); \
      } \
      renorm_q(qE, qO, m, q0, m0); \
    }

    if (tl == T) {
      uint4 A[8], Bv[8];
      float sA, sB;
#pragma unroll
      for (int r = 0; r < 8; ++r) A[r] = pl4[r];
      sA = pbb[lane];
#pragma unroll
      for (int r = 0; r < 8; ++r) Bv[r] = pl4[8 + r];
      sB = pbb[64 + lane];

      // chunk 0 (peeled t=0 init)
      q0 = readlane_f(sA, 0);                       // alpha[0](0) = p_blank
      qO = (lane == 0) ? geth64(A, 0) : 0.0f;       // alpha[1](0)
#pragma unroll
      for (int g = 0; g < 16; ++g) {
#pragma unroll
        for (int kk = 0; kk < 4; ++kk) {
          int k = g * 4 + kk;
          if (k == 0) continue;
          ctc_step_p(geth64(A, k), readlane_f(sA, k), skip_ok,
                     qE, qO, m, q0, m0);
        }
        renorm_q(qE, qO, m, q0, m0);
      }

#pragma unroll 1
      for (int c = 1; c < 8; c += 2) {
        if (c + 1 < 8) {
#pragma unroll
          for (int r = 0; r < 8; ++r) A[r] = pl4[(c + 1) * 8 + r];
          sA = pbb[(c + 1) * 64 + lane];
        }
        CONSUME(Bv, sB);                  // chunk c
        if (c + 2 < 8) {
#pragma unroll
          for (int r = 0; r < 8; ++r) Bv[r] = pl4[(c + 2) * 8 + r];
          sB = pbb[(c + 2) * 64 + lane];
        }
        if (c + 1 < 8) {
          CONSUME(A, sA);                 // chunk c+1
        }
      }
    } else {
      // general fallback (not exercised by this input shape)
      const __half* plh = (const __half*)pl4;
      q0 = pbb[0];
      qO = (lane == 0) ? __half2float(plh[0]) : 0.0f;
      for (int t = 1; t < tl; ++t) {
        ctc_step_p(__half2float(plh[t]), pbb[t], skip_ok, qE, qO, m, q0, m0);
        if ((t & 3) == 3) renorm_q(qE, qO, m, q0, m0);
      }
    }
#undef CONSUME
    // alpha[2ll] = qE, alpha[2ll-1] = qO at lane ll-1, both scaled by 2^m.
    float e1 = __shfl(qE, ll - 1);
    float e2 = __shfl(qO, ll - 1);
    int msel = __shfl(m, ll - 1);
    if (lane == 0) {
      float r = (float)msel + __builtin_amdgcn_logf(e1 + e2);   // log2 total
      loss_b[b] = -r * LN2;
    }
  } else {
    // ---------------- Myers edit distance (lane = sample) ----------------
    int bb = (blockIdx.x << 6) + lane;
    int tl = logit_len[bb];
    int ll = label_len[bb];
    int shift = ll - 1;
    u64 Pv = ~0ULL, Mv = 0ULL;
    int score = ll;
    int prevc = 255;
    const char* eqB = (const char*)(eqm + (size_t)bb * T);   // per-lane base
    const char* pqB = (const char*)(predc + (size_t)bb * T); // per-lane base
    auto stage = [&](int c, int s) {
      char* Eb = smem + s * 18432;
#pragma unroll
      for (int k = 0; k < 16; ++k)
        gload_lds16(eqB + (size_t)c * 256 + k * 16, Eb + k * 1024);
#pragma unroll
      for (int k = 0; k < 2; ++k)
        gload_lds16(pqB + (size_t)c * 32 + k * 16, Eb + 16384 + k * 1024);
    };
    stage(0, 0);
    WAIT_VM0();
    stage(1, 1);
#pragma unroll 1
    for (int c = 0; c < 16; ++c) {
      int s = c & 1;
      if (c) {
        WAIT_VM0();                       // chunk c ready
        if (c < 15) stage(c + 1, s ^ 1);  // prefetch next
      }
      const u64* ep = (const u64*)(smem + s * 18432);
      const unsigned char* pp = (const unsigned char*)(smem + s * 18432 + 16384);
#pragma unroll
      for (int k = 0; k < 32; ++k) {
        u64 eq = ep[(k >> 1) * 128 + lane * 2 + (k & 1)];
        int cc = pp[(k >> 4) * 1024 + lane * 16 + (k & 15)];
        ed_step(eq, cc, shift, c * 32 + k < tl, Pv, Mv, score, prevc);
      }
    }
    ler_b[bb] = (float)score / (float)ll;
  }
}

// ---------------------------------------------------------------------------
// K3: deterministic final mean over B for loss and ler.
// ---------------------------------------------------------------------------
__global__ __launch_bounds__(512) void reduce_kernel(
    const float* __restrict__ loss_b, const float* __restrict__ ler_b,
    float* __restrict__ out) {
  __shared__ float sl[512];
  __shared__ float sr[512];
  int tid = threadIdx.x;
  sl[tid] = loss_b[tid];
  sr[tid] = ler_b[tid];
  __syncthreads();
  for (int off = 256; off; off >>= 1) {
    if (tid < off) { sl[tid] += sl[tid + off]; sr[tid] += sr[tid + off]; }
    __syncthreads();
  }
  if (tid == 0) {
    out[0] = sl[0] / (float)B;
    out[1] = sr[0] / (float)B;
  }
}

extern "C" void kernel_launch(void* const* d_in, const int* in_sizes, int n_in,
                              void* d_out, int out_size, void* d_ws, size_t ws_size,
                              hipStream_t stream) {
  const int*   labels    = (const int*)d_in[0];
  const float* logits    = (const float*)d_in[1];
  const int*   label_len = (const int*)d_in[2];
  const int*   logit_len = (const int*)d_in[3];
  float* out = (float*)d_out;

  char* ws = (char*)d_ws;
  const size_t OFF_BL   = (size_t)B * T * 64 * 2;        // after 32MB p_lab
  const size_t OFF_EQM  = OFF_BL + (size_t)B * T * 4;    // after 1MB p_bl
  const size_t OFF_PRED = OFF_EQM + (size_t)B * T * 8;   // after 2MB eqm
  const size_t OFF_RED  = OFF_PRED + (size_t)B * T;      // after 0.25MB predc
  __half* p_lab = (__half*)ws;
  float*  p_bl  = (float*)(ws + OFF_BL);
  u64*    eqm   = (u64*)(ws + OFF_EQM);
  unsigned char* predc = (unsigned char*)(ws + OFF_PRED);
  float*  loss_b = (float*)(ws + OFF_RED);
  float*  ler_b  = loss_b + B;

  rowstats_kernel<<<B * (T / 64), 256, 0, stream>>>(logits, labels, p_lab,
                                                    p_bl, predc, eqm);
  dp_kernel<<<B + 8, 64, 0, stream>>>(p_lab, p_bl, predc, eqm, labels,
                                      label_len, logit_len, loss_b, ler_b);
  reduce_kernel<<<1, 512, 0, stream>>>(loss_b, ler_b, out);
}